// Round 7
// baseline (307.695 us; speedup 1.0000x reference)
//
#include <hip/hip_runtime.h>
#include <cstddef>
#include <cstdint>

#define BB 4
#define TT 2048
#define CC 1024
#define LL 256
#define HH 16
#define DD 64   // head size
#define QLD (CC + LL)  // 1280: row stride of fused q|latent buffer

typedef __attribute__((ext_vector_type(8))) short s16x8;
typedef __attribute__((ext_vector_type(4))) float f32x4;

static __device__ inline unsigned short f2bf(float f) {
    union { float f; unsigned u; } v; v.f = f;
    unsigned r = v.u + 0x7fffu + ((v.u >> 16) & 1u);  // RNE
    return (unsigned short)(r >> 16);
}

static __device__ inline float fast_exp2(float x) {
#if __has_builtin(__builtin_amdgcn_exp2f)
    return __builtin_amdgcn_exp2f(x);
#else
    return exp2f(x);
#endif
}

// pack two f32 -> two bf16 (truncation) in one v_perm_b32; lo -> low 16 bits
static __device__ inline unsigned pack_bf16_trunc(float lo, float hi) {
    union { float f; unsigned u; } a, b;
    a.f = lo; b.f = hi;
    return __builtin_amdgcn_perm(b.u, a.u, 0x07060302u);
}

// async global->LDS, 16B per lane; LDS dest = wave-uniform base + lane*16
#define GLDS16(g, l)                                             \
    __builtin_amdgcn_global_load_lds(                            \
        (__attribute__((address_space(1))) void*)(g),            \
        (__attribute__((address_space(3))) void*)(l), 16, 0, 0)

// ====================== fused conversion kernel =============================
// blocks [0, 8192): x fp32 -> bf16 (1024 elems/block)
// blocks [8192, 8896): one 64x64 transpose tile of a weight matrix
extern "C" __global__ __launch_bounds__(256)
void fused_cvt(const float* __restrict__ x, unsigned short* __restrict__ xb,
               const float* __restrict__ Wq, const float* __restrict__ Wkv,
               const float* __restrict__ Wk, const float* __restrict__ Wv,
               const float* __restrict__ Wo,
               unsigned short* __restrict__ W1t, unsigned short* __restrict__ W2t,
               unsigned short* __restrict__ Wot, float qscale) {
    __shared__ unsigned short Ts[64][72];
    const int t = threadIdx.x;
    int blk = blockIdx.x;
    if (blk < 8192) {
        const int i = blk * 256 + t;
        const float4 v = ((const float4*)x)[i];
        ushort4 o;
        o.x = f2bf(v.x); o.y = f2bf(v.y); o.z = f2bf(v.z); o.w = f2bf(v.w);
        ((ushort4*)xb)[i] = o;
        return;
    }
    blk -= 8192;
    const float* W; unsigned short* Wt; int K, N; float scale; int tile;
    if (blk < 256)      { W = Wq;  Wt = W1t;                      K = CC; N = CC; scale = qscale; tile = blk; }
    else if (blk < 320) { W = Wkv; Wt = W1t + (size_t)CC * CC;    K = CC; N = LL; scale = 1.f;    tile = blk - 256; }
    else if (blk < 384) { W = Wk;  Wt = W2t;                      K = LL; N = CC; scale = 1.f;    tile = blk - 320; }
    else if (blk < 448) { W = Wv;  Wt = W2t + (size_t)CC * LL;    K = LL; N = CC; scale = 1.f;    tile = blk - 384; }
    else                { W = Wo;  Wt = Wot;                      K = CC; N = CC; scale = 1.f;    tile = blk - 448; }
    const int ktiles = K >> 6;
    const int k0 = (tile % ktiles) * 64, n0 = (tile / ktiles) * 64;
#pragma unroll
    for (int l = 0; l < 4; ++l) {
        const int idx = t + l * 256;
        const int r = idx >> 4, c4 = (idx & 15) * 4;
        const float4 v = *(const float4*)(W + (size_t)(k0 + r) * N + n0 + c4);
        Ts[c4 + 0][r] = f2bf(v.x * scale); Ts[c4 + 1][r] = f2bf(v.y * scale);
        Ts[c4 + 2][r] = f2bf(v.z * scale); Ts[c4 + 3][r] = f2bf(v.w * scale);
    }
    __syncthreads();
#pragma unroll
    for (int l = 0; l < 2; ++l) {
        const int idx = t + l * 256;
        const int n = idx >> 3, seg = idx & 7;
        *(s16x8*)(Wt + (size_t)(n0 + n) * K + k0 + seg * 8) = *(const s16x8*)&Ts[n][seg * 8];
    }
}

// ========== bf16 MFMA GEMM: C[M,N] = A[M,K] @ Bt[N,K]^T ====================
// 128x128 tile, BK=64, 256 threads = 4 waves (2x2), 4x4 16x16x32 MFMA per wave.
// Staging via global_load_lds with XOR source swizzle. XCD-aware bijective
// block swizzle (T1, verified +8.6us in r5).
// MODE 0: fp32 store (ldc) | MODE 1: bf16 store (ldc)
// MODE 3: cols < CC -> bf16 store (ldc); cols >= CC -> transposed vt store
template <int MODE>
__global__ __launch_bounds__(256)
void bgemm(const unsigned short* __restrict__ A, const unsigned short* __restrict__ Bt,
           void* __restrict__ Cv, void* __restrict__ Cv2,
           int M, int N, int K, int lda, int ldc) {
    __shared__ unsigned short As[128][64];
    __shared__ unsigned short Bs[128][64];
    const int t = threadIdx.x;
    const int w = t >> 6, lane = t & 63, quad = lane >> 4, l16 = lane & 15;
    const int wm = w & 1, wn = w >> 1;

    // XCD-aware swizzle: wg -> (wg%8)*(nwg/8) + wg/8 (bijective when nwg%8==0)
    int wg = blockIdx.y * gridDim.x + blockIdx.x;
    const int nwg = gridDim.x * gridDim.y;
    if ((nwg & 7) == 0) wg = (wg & 7) * (nwg >> 3) + (wg >> 3);
    const int bx = wg % gridDim.x, by = wg / gridDim.x;
    const int row0 = by * 128, col0 = bx * 128;

    const int sr = lane >> 3;                 // row within an 8-row chunk
    const int sc = ((lane & 7) ^ sr) * 8;     // swizzled 16B source segment

    f32x4 acc[4][4];
#pragma unroll
    for (int i = 0; i < 4; ++i)
#pragma unroll
        for (int j = 0; j < 4; ++j) acc[i][j] = (f32x4){0.f, 0.f, 0.f, 0.f};

    const unsigned short* Ab = A + (size_t)(row0 + w * 32 + sr) * lda + sc;
    const unsigned short* Bb = Bt + (size_t)(col0 + w * 32 + sr) * K + sc;

    for (int k0 = 0; k0 < K; k0 += 64) {
#pragma unroll
        for (int c = 0; c < 4; ++c) {
            GLDS16(Ab + (size_t)(c * 8) * lda + k0, &As[w * 32 + c * 8][0]);
            GLDS16(Bb + (size_t)(c * 8) * K + k0, &Bs[w * 32 + c * 8][0]);
        }
        __syncthreads();
#pragma unroll
        for (int kk = 0; kk < 2; ++kk) {
            s16x8 af[4], bfr[4];
#pragma unroll
            for (int mt = 0; mt < 4; ++mt)
                af[mt] = *(const s16x8*)
                    &As[wm * 64 + mt * 16 + l16][((kk * 4 + quad) ^ (l16 & 7)) * 8];
#pragma unroll
            for (int nt = 0; nt < 4; ++nt)
                bfr[nt] = *(const s16x8*)
                    &Bs[wn * 64 + nt * 16 + l16][((kk * 4 + quad) ^ (l16 & 7)) * 8];
#pragma unroll
            for (int mt = 0; mt < 4; ++mt)
#pragma unroll
                for (int nt = 0; nt < 4; ++nt)
                    acc[mt][nt] = __builtin_amdgcn_mfma_f32_16x16x32_bf16(
                        af[mt], bfr[nt], acc[mt][nt], 0, 0, 0);
        }
        __syncthreads();
    }

    if constexpr (MODE == 0) {
        float* C = (float*)Cv;
#pragma unroll
        for (int mt = 0; mt < 4; ++mt)
#pragma unroll
            for (int nt = 0; nt < 4; ++nt)
#pragma unroll
                for (int r = 0; r < 4; ++r)
                    C[(size_t)(row0 + wm * 64 + mt * 16 + quad * 4 + r) * ldc +
                      col0 + wn * 64 + nt * 16 + l16] = acc[mt][nt][r];
    } else if constexpr (MODE == 1) {
        unsigned short* C = (unsigned short*)Cv;
#pragma unroll
        for (int mt = 0; mt < 4; ++mt)
#pragma unroll
            for (int nt = 0; nt < 4; ++nt)
#pragma unroll
                for (int r = 0; r < 4; ++r)
                    C[(size_t)(row0 + wm * 64 + mt * 16 + quad * 4 + r) * ldc +
                      col0 + wn * 64 + nt * 16 + l16] = f2bf(acc[mt][nt][r]);
    } else {
        if (col0 < CC) {
            unsigned short* C = (unsigned short*)Cv;
#pragma unroll
            for (int mt = 0; mt < 4; ++mt)
#pragma unroll
                for (int nt = 0; nt < 4; ++nt)
#pragma unroll
                    for (int r = 0; r < 4; ++r)
                        C[(size_t)(row0 + wm * 64 + mt * 16 + quad * 4 + r) * ldc +
                          col0 + wn * 64 + nt * 16 + l16] = f2bf(acc[mt][nt][r]);
        } else {
            // v-half: transposed store vt[b][h][dv][t]
            __shared__ unsigned short Tb[64][136];
            unsigned short* vt = (unsigned short*)Cv2;
            const int b   = row0 >> 11;  // 2048 tokens per batch; tile never crosses
            const int tl0 = row0 & 2047;
#pragma unroll
            for (int h = 0; h < 2; ++h) {
                if (wn == h) {
#pragma unroll
                    for (int mt = 0; mt < 4; ++mt)
#pragma unroll
                        for (int nt = 0; nt < 4; ++nt)
#pragma unroll
                            for (int r = 0; r < 4; ++r)
                                Tb[nt * 16 + l16][wm * 64 + mt * 16 + quad * 4 + r] =
                                    f2bf(acc[mt][nt][r]);
                }
                __syncthreads();
                const int head = ((col0 - CC) >> 6) + h;
#pragma unroll
                for (int l = 0; l < 4; ++l) {
                    const int idx = t + l * 256;
                    const int dv = idx >> 4, seg = idx & 15;
                    *(s16x8*)(vt + (((size_t)b * HH + head) * DD + dv) * TT + tl0 + seg * 8) =
                        *(const s16x8*)&Tb[dv][seg * 8];
                }
                __syncthreads();
            }
        }
    }
}

// ======= Flash attention v6: barrier-free paired waves, reg-pipelined K/V ===
// Synthesis of r0-r6 evidence: block-barrier structures stall 2.1-5.7us/step
// regardless of inner work (r1/r2/r3/r6); r4's barrier-free waves failed from
// (a) tail-decayed 1-wave occupancy and (b) load->use serialization per nt.
// This version fixes both:
//  - QBLK=32 per wave, q-tile (63-p) PAIRED with p -> every wave exactly 33
//    64-key tile-steps; 2048 waves = 8 waves/CU FLAT (2/SIMD), no tail.
//  - K/V fragments live in registers, explicitly DOUBLE-BUFFERED: the next
//    tile's 16x16B loads are issued before computing the current tile from
//    the other bank; compiler's counted-vmcnt covers L2 latency with the
//    ~1000-cyc compute phase. No LDS, no barriers, nothing to convoy.
// 4 waves/block (256 thr) purely for dispatch efficiency; waves independent.
// Same-bh blocks are 64 apart in linear id -> same XCD -> shared K/V L2 hits.
// Frag layouts verified on HW in r4 (passed); softmax permlane dance r2.
extern "C" __global__ __launch_bounds__(256, 2)
void mla_attn5(const unsigned short* __restrict__ q,
               const unsigned short* __restrict__ k,
               const unsigned short* __restrict__ vt,
               unsigned short* __restrict__ y) {
    const int bh = blockIdx.x;            // 0..63
    const int b = bh >> 4, h = bh & 15;
    const int w = threadIdx.x >> 6;
    const int pidx = blockIdx.y * 4 + w;  // 0..31 (pair index, one per wave)
    const int lane = threadIdx.x & 63, quad = lane >> 4, l16 = lane & 15;

    // per-lane fragment row bases (16B-aligned)
    const unsigned short* kbl = k + ((size_t)b * TT) * CC + h * DD + quad * 8 +
                                (size_t)l16 * CC;
    const unsigned short* vbl = vt + ((size_t)(b * HH + h)) * DD * TT + quad * 8 +
                                (size_t)l16 * TT;

// load one 64-key tile's K and V fragments into a register bank
#define LOAD_FRAGS(KF, VF, s0_)                                                \
    do {                                                                       \
        _Pragma("unroll")                                                      \
        for (int nt_ = 0; nt_ < 4; ++nt_) {                                    \
            const unsigned short* kr_ = kbl + (size_t)((s0_) + nt_ * 16) * CC; \
            KF[nt_][0] = *(const s16x8*)(kr_);                                 \
            KF[nt_][1] = *(const s16x8*)(kr_ + 32);                            \
            const unsigned short* vr_ = vbl + (size_t)(nt_ * 16) * TT + (s0_); \
            VF[nt_][0] = *(const s16x8*)(vr_);                                 \
            VF[nt_][1] = *(const s16x8*)(vr_ + 32);                            \
        }                                                                      \
    } while (0)

// S^T -> softmax -> reg-P redistribution -> PV, for one 64-key tile
#define COMPUTE_TILE(KF, VF, s0_)                                              \
    do {                                                                       \
        const bool masked_ = ((s0_) + 63 > qw0);  /* wave-uniform */           \
        _Pragma("unroll")                                                      \
        for (int qs_ = 0; qs_ < 2; ++qs_) {                                    \
            f32x4 st_[4];                                                      \
            _Pragma("unroll")                                                  \
            for (int nt_ = 0; nt_ < 4; ++nt_) {                                \
                f32x4 a_ = (f32x4){0.f, 0.f, 0.f, 0.f};                        \
                a_ = __builtin_amdgcn_mfma_f32_16x16x32_bf16(                  \
                    KF[nt_][0], qf[qs_][0], a_, 0, 0, 0);                      \
                a_ = __builtin_amdgcn_mfma_f32_16x16x32_bf16(                  \
                    KF[nt_][1], qf[qs_][1], a_, 0, 0, 0);                      \
                st_[nt_] = a_;                                                 \
            }                                                                  \
            const int qidx_ = qw0 + qs_ * 16 + l16;                            \
            unsigned pc_[4][2];                                                \
            float ts_ = 0.f;                                                   \
            _Pragma("unroll")                                                  \
            for (int nt_ = 0; nt_ < 4; ++nt_) {                                \
                const int key0_ = (s0_) + nt_ * 16 + quad * 4;                 \
                float pv_[4];                                                  \
                _Pragma("unroll")                                              \
                for (int r_ = 0; r_ < 4; ++r_) {                               \
                    float sv_ = st_[nt_][r_];                                  \
                    if (masked_ && (key0_ + r_ > qidx_)) sv_ = -1e30f;         \
                    pv_[r_] = fast_exp2(sv_);                                  \
                }                                                              \
                ts_ += (pv_[0] + pv_[1]) + (pv_[2] + pv_[3]);                  \
                pc_[nt_][0] = pack_bf16_trunc(pv_[0], pv_[1]);                 \
                pc_[nt_][1] = pack_bf16_trunc(pv_[2], pv_[3]);                 \
            }                                                                  \
            lsum[qs_] += ts_;                                                  \
            s16x8 pf_[2];                                                      \
            _Pragma("unroll")                                                  \
            for (int kh_ = 0; kh_ < 2; ++kh_) {                                \
                auto sa_ = __builtin_amdgcn_permlane32_swap(                   \
                    (int)pc_[2 * kh_ + 0][0], (int)pc_[2 * kh_ + 1][0],        \
                    false, false);                                             \
                auto w02_ = __builtin_amdgcn_permlane16_swap(                  \
                    sa_[0], sa_[1], false, false);                             \
                auto sb_ = __builtin_amdgcn_permlane32_swap(                   \
                    (int)pc_[2 * kh_ + 0][1], (int)pc_[2 * kh_ + 1][1],        \
                    false, false);                                             \
                auto w13_ = __builtin_amdgcn_permlane16_swap(                  \
                    sb_[0], sb_[1], false, false);                             \
                union { unsigned u[4]; s16x8 v; } fu_;                         \
                fu_.u[0] = (unsigned)w02_[0];  /* keys +0,+1 */                \
                fu_.u[1] = (unsigned)w13_[0];  /* keys +2,+3 */                \
                fu_.u[2] = (unsigned)w02_[1];  /* keys +4,+5 */                \
                fu_.u[3] = (unsigned)w13_[1];  /* keys +6,+7 */                \
                pf_[kh_] = fu_.v;                                              \
            }                                                                  \
            _Pragma("unroll")                                                  \
            for (int nt_ = 0; nt_ < 4; ++nt_) {                                \
                o[qs_][nt_] = __builtin_amdgcn_mfma_f32_16x16x32_bf16(         \
                    pf_[0], VF[nt_][0], o[qs_][nt_], 0, 0, 0);                 \
                o[qs_][nt_] = __builtin_amdgcn_mfma_f32_16x16x32_bf16(         \
                    pf_[1], VF[nt_][1], o[qs_][nt_], 0, 0, 0);                 \
            }                                                                  \
        }                                                                      \
    } while (0)

#pragma unroll 1
    for (int item = 0; item < 2; ++item) {
        const int qt = (item == 0) ? (63 - pidx) : pidx;  // heavy first
        const int qw0 = qt * 32;           // wave's first query
        const int nkt = (qt >> 1) + 1;     // 64-key tiles needed

        // Q fragments (pre-scaled by 0.125*log2(e) via Wq)
        s16x8 qf[2][2];
#pragma unroll
        for (int qs = 0; qs < 2; ++qs)
#pragma unroll
            for (int kh = 0; kh < 2; ++kh)
                qf[qs][kh] = *(const s16x8*)(q + ((size_t)b * TT + qw0 + qs * 16 + l16) * QLD +
                                             h * DD + kh * 32 + quad * 8);

        f32x4 o[2][4];
        float lsum[2] = {0.f, 0.f};
#pragma unroll
        for (int qs = 0; qs < 2; ++qs)
#pragma unroll
            for (int nt = 0; nt < 4; ++nt) o[qs][nt] = (f32x4){0.f, 0.f, 0.f, 0.f};

        // software-pipelined tile loop: static 2-bank register double-buffer
        s16x8 kfA[4][2], vfA[4][2], kfB[4][2], vfB[4][2];
        LOAD_FRAGS(kfA, vfA, 0);
        int kt = 0;
#pragma unroll 1
        for (;;) {
            if (kt + 1 < nkt) LOAD_FRAGS(kfB, vfB, (kt + 1) * 64);
            COMPUTE_TILE(kfA, vfA, kt * 64);
            if (++kt >= nkt) break;
            if (kt + 1 < nkt) LOAD_FRAGS(kfA, vfA, (kt + 1) * 64);
            COMPUTE_TILE(kfB, vfB, kt * 64);
            if (++kt >= nkt) break;
        }

        // final l reduction: quads hold partial sums for query qs*16+l16
        float lfull[2];
#pragma unroll
        for (int qs = 0; qs < 2; ++qs) {
            float s = lsum[qs];
            s += __shfl_xor(s, 16);
            s += __shfl_xor(s, 32);
            lfull[qs] = s;
        }

        // store: o element = (query qs*16+quad*4+r, dv nt*16+l16)
#pragma unroll
        for (int qs = 0; qs < 2; ++qs) {
#pragma unroll
            for (int r = 0; r < 4; ++r) {
                const float inv = 1.f / __shfl(lfull[qs], quad * 4 + r);
                unsigned short* yb = y + ((size_t)b * TT + qw0 + qs * 16 + quad * 4 + r) * CC +
                                     h * DD + l16;
#pragma unroll
                for (int nt = 0; nt < 4; ++nt)
                    yb[nt * 16] = f2bf(o[qs][nt][r] * inv);
            }
        }
    }
#undef LOAD_FRAGS
#undef COMPUTE_TILE
}

extern "C" void kernel_launch(void* const* d_in, const int* in_sizes, int n_in,
                              void* d_out, int out_size, void* d_ws, size_t ws_size,
                              hipStream_t stream) {
    const float* x   = (const float*)d_in[0];
    const float* Wq  = (const float*)d_in[1];
    const float* Wkv = (const float*)d_in[2];
    const float* Wk  = (const float*)d_in[3];
    const float* Wv  = (const float*)d_in[4];
    const float* Wo  = (const float*)d_in[5];
    float* out = (float*)d_out;

    const int M = BB * TT;  // 8192
    unsigned short* p = (unsigned short*)d_ws;
    unsigned short* xb    = p; p += (size_t)M * CC;     // bf16 x
    unsigned short* qlatb = p; p += (size_t)M * QLD;    // fused q | latent
    unsigned short* kb    = p; p += (size_t)M * CC;
    unsigned short* vtb   = p; p += (size_t)M * CC;
    unsigned short* yb    = p; p += (size_t)M * CC;
    unsigned short* W1t   = p; p += (size_t)QLD * CC;   // [Wq^T ; Wkv^T]  [1280][1024]
    unsigned short* W2t   = p; p += (size_t)(2 * CC) * LL;  // [Wk^T ; Wv^T] [2048][256]
    unsigned short* Wot   = p; p += (size_t)CC * CC;

    const float qscale = 0.125f * 1.44269504f;  // 1/sqrt(64) * log2(e), folded into Wq

    fused_cvt<<<8896, 256, 0, stream>>>(x, xb, Wq, Wkv, Wk, Wv, Wo,
                                        W1t, W2t, Wot, qscale);
    // fused q|latent projection: [M,1280] = x @ [Wq | Wkv]
    bgemm<1><<<dim3(QLD / 128, M / 128), 256, 0, stream>>>(
        xb, W1t, qlatb, nullptr, M, QLD, CC, CC, QLD);
    // fused k|v up-projection: k half -> kb, v half -> vtb (transposed)
    bgemm<3><<<dim3(2 * CC / 128, M / 128), 256, 0, stream>>>(
        qlatb + CC, W2t, kb, vtb, M, 2 * CC, LL, QLD, CC);
    mla_attn5<<<dim3(BB * HH, 8), 256, 0, stream>>>(qlatb, kb, vtb, yb);
    bgemm<0><<<dim3(CC / 128, M / 128), 256, 0, stream>>>(
        yb, Wot, out, nullptr, M, CC, CC, CC, CC);
}

// Round 8
// 231.409 us; speedup vs baseline: 1.3297x; 1.3297x over previous
//
#include <hip/hip_runtime.h>
#include <cstddef>
#include <cstdint>

#define BB 4
#define TT 2048
#define CC 1024
#define LL 256
#define HH 16
#define DD 64   // head size
#define QLD (CC + LL)  // 1280: row stride of fused q|latent buffer

typedef __attribute__((ext_vector_type(8))) short s16x8;
typedef __attribute__((ext_vector_type(4))) float f32x4;

static __device__ inline unsigned short f2bf(float f) {
    union { float f; unsigned u; } v; v.f = f;
    unsigned r = v.u + 0x7fffu + ((v.u >> 16) & 1u);  // RNE
    return (unsigned short)(r >> 16);
}

static __device__ inline float fast_exp2(float x) {
#if __has_builtin(__builtin_amdgcn_exp2f)
    return __builtin_amdgcn_exp2f(x);
#else
    return exp2f(x);
#endif
}

// pack two f32 -> two bf16 (truncation) in one v_perm_b32; lo -> low 16 bits
static __device__ inline unsigned pack_bf16_trunc(float lo, float hi) {
    union { float f; unsigned u; } a, b;
    a.f = lo; b.f = hi;
    return __builtin_amdgcn_perm(b.u, a.u, 0x07060302u);
}

// async global->LDS, 16B per lane; LDS dest = wave-uniform base + lane*16
#define GLDS16(g, l)                                             \
    __builtin_amdgcn_global_load_lds(                            \
        (__attribute__((address_space(1))) void*)(g),            \
        (__attribute__((address_space(3))) void*)(l), 16, 0, 0)

// ====================== fused conversion kernel =============================
// blocks [0, 8192): x fp32 -> bf16 (1024 elems/block)
// blocks [8192, 8896): one 64x64 transpose tile of a weight matrix
extern "C" __global__ __launch_bounds__(256)
void fused_cvt(const float* __restrict__ x, unsigned short* __restrict__ xb,
               const float* __restrict__ Wq, const float* __restrict__ Wkv,
               const float* __restrict__ Wk, const float* __restrict__ Wv,
               const float* __restrict__ Wo,
               unsigned short* __restrict__ W1t, unsigned short* __restrict__ W2t,
               unsigned short* __restrict__ Wot, float qscale) {
    __shared__ unsigned short Ts[64][72];
    const int t = threadIdx.x;
    int blk = blockIdx.x;
    if (blk < 8192) {
        const int i = blk * 256 + t;
        const float4 v = ((const float4*)x)[i];
        ushort4 o;
        o.x = f2bf(v.x); o.y = f2bf(v.y); o.z = f2bf(v.z); o.w = f2bf(v.w);
        ((ushort4*)xb)[i] = o;
        return;
    }
    blk -= 8192;
    const float* W; unsigned short* Wt; int K, N; float scale; int tile;
    if (blk < 256)      { W = Wq;  Wt = W1t;                      K = CC; N = CC; scale = qscale; tile = blk; }
    else if (blk < 320) { W = Wkv; Wt = W1t + (size_t)CC * CC;    K = CC; N = LL; scale = 1.f;    tile = blk - 256; }
    else if (blk < 384) { W = Wk;  Wt = W2t;                      K = LL; N = CC; scale = 1.f;    tile = blk - 320; }
    else if (blk < 448) { W = Wv;  Wt = W2t + (size_t)CC * LL;    K = LL; N = CC; scale = 1.f;    tile = blk - 384; }
    else                { W = Wo;  Wt = Wot;                      K = CC; N = CC; scale = 1.f;    tile = blk - 448; }
    const int ktiles = K >> 6;
    const int k0 = (tile % ktiles) * 64, n0 = (tile / ktiles) * 64;
#pragma unroll
    for (int l = 0; l < 4; ++l) {
        const int idx = t + l * 256;
        const int r = idx >> 4, c4 = (idx & 15) * 4;
        const float4 v = *(const float4*)(W + (size_t)(k0 + r) * N + n0 + c4);
        Ts[c4 + 0][r] = f2bf(v.x * scale); Ts[c4 + 1][r] = f2bf(v.y * scale);
        Ts[c4 + 2][r] = f2bf(v.z * scale); Ts[c4 + 3][r] = f2bf(v.w * scale);
    }
    __syncthreads();
#pragma unroll
    for (int l = 0; l < 2; ++l) {
        const int idx = t + l * 256;
        const int n = idx >> 3, seg = idx & 7;
        *(s16x8*)(Wt + (size_t)(n0 + n) * K + k0 + seg * 8) = *(const s16x8*)&Ts[n][seg * 8];
    }
}

// ========== bf16 MFMA GEMM: C[M,N] = A[M,K] @ Bt[N,K]^T ====================
// 128x128 tile, BK=64, 256 threads = 4 waves (2x2), 4x4 16x16x32 MFMA per wave.
// Staging via global_load_lds with XOR source swizzle. XCD-aware bijective
// block swizzle (T1, verified +8.6us in r5).
// MODE 0: fp32 store (ldc) | MODE 1: bf16 store (ldc)
template <int MODE>
__global__ __launch_bounds__(256)
void bgemm(const unsigned short* __restrict__ A, const unsigned short* __restrict__ Bt,
           void* __restrict__ Cv, void* __restrict__ Cv2,
           int M, int N, int K, int lda, int ldc) {
    __shared__ unsigned short As[128][64];
    __shared__ unsigned short Bs[128][64];
    const int t = threadIdx.x;
    const int w = t >> 6, lane = t & 63, quad = lane >> 4, l16 = lane & 15;
    const int wm = w & 1, wn = w >> 1;

    // XCD-aware swizzle: wg -> (wg%8)*(nwg/8) + wg/8 (bijective when nwg%8==0)
    int wg = blockIdx.y * gridDim.x + blockIdx.x;
    const int nwg = gridDim.x * gridDim.y;
    if ((nwg & 7) == 0) wg = (wg & 7) * (nwg >> 3) + (wg >> 3);
    const int bx = wg % gridDim.x, by = wg / gridDim.x;
    const int row0 = by * 128, col0 = bx * 128;

    const int sr = lane >> 3;                 // row within an 8-row chunk
    const int sc = ((lane & 7) ^ sr) * 8;     // swizzled 16B source segment

    f32x4 acc[4][4];
#pragma unroll
    for (int i = 0; i < 4; ++i)
#pragma unroll
        for (int j = 0; j < 4; ++j) acc[i][j] = (f32x4){0.f, 0.f, 0.f, 0.f};

    const unsigned short* Ab = A + (size_t)(row0 + w * 32 + sr) * lda + sc;
    const unsigned short* Bb = Bt + (size_t)(col0 + w * 32 + sr) * K + sc;

    for (int k0 = 0; k0 < K; k0 += 64) {
#pragma unroll
        for (int c = 0; c < 4; ++c) {
            GLDS16(Ab + (size_t)(c * 8) * lda + k0, &As[w * 32 + c * 8][0]);
            GLDS16(Bb + (size_t)(c * 8) * K + k0, &Bs[w * 32 + c * 8][0]);
        }
        __syncthreads();
#pragma unroll
        for (int kk = 0; kk < 2; ++kk) {
            s16x8 af[4], bfr[4];
#pragma unroll
            for (int mt = 0; mt < 4; ++mt)
                af[mt] = *(const s16x8*)
                    &As[wm * 64 + mt * 16 + l16][((kk * 4 + quad) ^ (l16 & 7)) * 8];
#pragma unroll
            for (int nt = 0; nt < 4; ++nt)
                bfr[nt] = *(const s16x8*)
                    &Bs[wn * 64 + nt * 16 + l16][((kk * 4 + quad) ^ (l16 & 7)) * 8];
#pragma unroll
            for (int mt = 0; mt < 4; ++mt)
#pragma unroll
                for (int nt = 0; nt < 4; ++nt)
                    acc[mt][nt] = __builtin_amdgcn_mfma_f32_16x16x32_bf16(
                        af[mt], bfr[nt], acc[mt][nt], 0, 0, 0);
        }
        __syncthreads();
    }

    if constexpr (MODE == 0) {
        float* C = (float*)Cv;
#pragma unroll
        for (int mt = 0; mt < 4; ++mt)
#pragma unroll
            for (int nt = 0; nt < 4; ++nt)
#pragma unroll
                for (int r = 0; r < 4; ++r)
                    C[(size_t)(row0 + wm * 64 + mt * 16 + quad * 4 + r) * ldc +
                      col0 + wn * 64 + nt * 16 + l16] = acc[mt][nt][r];
    } else {
        unsigned short* C = (unsigned short*)Cv;
#pragma unroll
        for (int mt = 0; mt < 4; ++mt)
#pragma unroll
            for (int nt = 0; nt < 4; ++nt)
#pragma unroll
                for (int r = 0; r < 4; ++r)
                    C[(size_t)(row0 + wm * 64 + mt * 16 + quad * 4 + r) * ldc +
                      col0 + wn * 64 + nt * 16 + l16] = f2bf(acc[mt][nt][r]);
    }
}

// ====== bgemm_k256: C[8192,2048] = A[8192,256] @ Bt[2048,256]^T =============
// K=256 staged WHOLE: As[128][256]+Bs[128][256] = 128 KB LDS (1 block/CU),
// ONE stage + ONE barrier per block instead of 4 stage/sync rounds at BK=64 —
// the K=256 GEMM was barrier/stage-amortization-bound (4 K-steps only).
// Source-XOR swizzle confined to the low-3 bits of the 32 16B-segments per
// row (write side gs = (seg&24)|((seg^row)&7); read side mirrors it) keeps
// ds_read_b128 at the free 2-way banking, same family as bgemm's verified
// swizzle. Epilogue = bgemm MODE3: cols<CC -> bf16 k-store; cols>=CC ->
// transposed vt store. Tb ALIASES As (post-compute, barrier-protected) to
// stay at exactly 128 KB.
extern "C" __global__ __launch_bounds__(256)
void bgemm_k256(const unsigned short* __restrict__ A,
                const unsigned short* __restrict__ Bt,
                unsigned short* __restrict__ Ck,
                unsigned short* __restrict__ vt) {
    __shared__ unsigned short As[128][256];
    __shared__ unsigned short Bs[128][256];
    const int t = threadIdx.x;
    const int w = t >> 6, lane = t & 63, quad = lane >> 4, l16 = lane & 15;
    const int wm = w & 1, wn = w >> 1;

    // XCD-aware bijective swizzle (nwg = 16*64 = 1024, %8 == 0)
    int wg = blockIdx.y * gridDim.x + blockIdx.x;
    const int nwg = gridDim.x * gridDim.y;
    wg = (wg & 7) * (nwg >> 3) + (wg >> 3);
    const int bx = wg % gridDim.x, by = wg / gridDim.x;
    const int row0 = by * 128, col0 = bx * 128;

    // ---- stage the whole K=256 panel: per GLDS16, 64 lanes = 2 rows x 32 segs
    const int sr2 = lane >> 5;   // row within pair
    const int seg = lane & 31;   // 16B segment within row
#pragma unroll
    for (int g = 0; g < 16; ++g) {
        const int ra = w * 32 + g * 2 + sr2;
        const int ga = ((seg & 24) | ((seg ^ ra) & 7)) * 8;  // swizzled src col
        GLDS16(A + (size_t)(row0 + ra) * QLD + ga, &As[w * 32 + g * 2][0]);
        GLDS16(Bt + (size_t)(col0 + ra) * 256 + ga, &Bs[w * 32 + g * 2][0]);
    }
    __syncthreads();  // single vmcnt(0)+barrier for the whole block

    f32x4 acc[4][4];
#pragma unroll
    for (int i = 0; i < 4; ++i)
#pragma unroll
        for (int j = 0; j < 4; ++j) acc[i][j] = (f32x4){0.f, 0.f, 0.f, 0.f};

#pragma unroll
    for (int kk = 0; kk < 8; ++kk) {
        const int sn = kk * 4 + quad;
        const int cs = ((sn & 24) | ((sn ^ l16) & 7)) * 8;  // swizzled read col
        s16x8 af[4], bfr[4];
#pragma unroll
        for (int mt = 0; mt < 4; ++mt)
            af[mt] = *(const s16x8*)&As[wm * 64 + mt * 16 + l16][cs];
#pragma unroll
        for (int nt = 0; nt < 4; ++nt)
            bfr[nt] = *(const s16x8*)&Bs[wn * 64 + nt * 16 + l16][cs];
#pragma unroll
        for (int mt = 0; mt < 4; ++mt)
#pragma unroll
            for (int nt = 0; nt < 4; ++nt)
                acc[mt][nt] = __builtin_amdgcn_mfma_f32_16x16x32_bf16(
                    af[mt], bfr[nt], acc[mt][nt], 0, 0, 0);
    }

    if (col0 < CC) {
        // k-half: plain bf16 store, ldc = CC
#pragma unroll
        for (int mt = 0; mt < 4; ++mt)
#pragma unroll
            for (int nt = 0; nt < 4; ++nt)
#pragma unroll
                for (int r = 0; r < 4; ++r)
                    Ck[(size_t)(row0 + wm * 64 + mt * 16 + quad * 4 + r) * CC +
                       col0 + wn * 64 + nt * 16 + l16] = f2bf(acc[mt][nt][r]);
    } else {
        // v-half: transposed store vt[b][h][dv][t]; Tb aliases As (done with it)
        __syncthreads();  // ensure ALL waves finished reading As before overwrite
        unsigned short (*Tb)[136] = (unsigned short(*)[136]) & As[0][0];
        const int b   = row0 >> 11;  // 2048 tokens per batch; tile never crosses
        const int tl0 = row0 & 2047;
#pragma unroll
        for (int h = 0; h < 2; ++h) {
            if (wn == h) {
#pragma unroll
                for (int mt = 0; mt < 4; ++mt)
#pragma unroll
                    for (int nt = 0; nt < 4; ++nt)
#pragma unroll
                        for (int r = 0; r < 4; ++r)
                            Tb[nt * 16 + l16][wm * 64 + mt * 16 + quad * 4 + r] =
                                f2bf(acc[mt][nt][r]);
            }
            __syncthreads();
            const int head = ((col0 - CC) >> 6) + h;
#pragma unroll
            for (int l = 0; l < 4; ++l) {
                const int idx = t + l * 256;
                const int dv = idx >> 4, sg = idx & 15;
                *(s16x8*)(vt + (((size_t)b * HH + head) * DD + dv) * TT + tl0 + sg * 8) =
                    *(const s16x8*)&Tb[dv][sg * 8];
            }
            __syncthreads();
        }
    }
}

// ================= Flash attention v2 (r2/r5 structure) + phase stagger =====
// grid (B*H, TT/128) with qt2 REVERSED (heaviest blocks dispatch first).
// 256 threads = 4 waves; wave w owns 32 queries. P fully in registers
// (permlane redistribution, verified r2). K/V double-buffered.
// Verified 67-68us across three rounds; structural alternatives (KVBLK=128,
// 1-wave no-LDS, paired 2-wave, reg-dbuf barrier-free) all regressed.
extern "C" __global__ __launch_bounds__(256, 4)
void mla_attn2(const unsigned short* __restrict__ q,
               const unsigned short* __restrict__ k,
               const unsigned short* __restrict__ vt,
               unsigned short* __restrict__ y) {
    __shared__ unsigned short Ks[2][64][64];  // [buf][key][d], source-XOR-swizzled segs
    __shared__ unsigned short Vs[2][64][64];  // [buf][dv][key], source-XOR-swizzled segs

    // phase stagger (wave-uniform, one-time)
    {
        const unsigned bid = blockIdx.y * gridDim.x + blockIdx.x;
        const unsigned stag = (bid * 0x9E3779B1u) >> 30;  // 2 well-mixed bits
        for (unsigned i = 0; i < stag; ++i) __builtin_amdgcn_s_sleep(23);
    }

    const int bh = blockIdx.x;
    const int qt2 = (gridDim.y - 1) - blockIdx.y;  // big blocks first (LPT packing)
    const int b = bh >> 4, h = bh & 15;
    const int t0 = qt2 * 128;
    const int t = threadIdx.x;
    const int w = t >> 6, lane = t & 63, quad = lane >> 4, l16 = lane & 15;
    const int qw0 = t0 + w * 32;                       // wave's first query
    const int swz = ((lane & 7) ^ ((lane >> 3) & 7)) * 8;  // swizzled source seg
    const int lrow = lane >> 3;                        // row within 8-row chunk

    const unsigned short* kb0 = k + ((size_t)b * TT) * CC + h * DD;
    const unsigned short* vb0 = vt + ((size_t)(b * HH + h)) * DD * TT;

    // Q fragments straight from global (pre-scaled), hoisted
    s16x8 qf[2][2];
#pragma unroll
    for (int qs = 0; qs < 2; ++qs)
#pragma unroll
        for (int kh = 0; kh < 2; ++kh)
            qf[qs][kh] = *(const s16x8*)(q + ((size_t)b * TT + qw0 + qs * 16 + l16) * QLD +
                                         h * DD + kh * 32 + quad * 8);

    f32x4 o[2][4];
    float lsum[2] = {0.f, 0.f};
#pragma unroll
    for (int qs = 0; qs < 2; ++qs)
#pragma unroll
        for (int nt = 0; nt < 4; ++nt) o[qs][nt] = (f32x4){0.f, 0.f, 0.f, 0.f};

    const int nkt = 2 * qt2 + 2;

    // stage K,V tiles into buffer bi_: wave w covers chunks g=w*2..w*2+1 (8 rows each)
#define STAGE_KV(kt_, bi_)                                                     \
    do {                                                                       \
        const int s0_ = (kt_) * 64;                                            \
        _Pragma("unroll")                                                      \
        for (int c = 0; c < 2; ++c) {                                          \
            const int g = w * 2 + c;                                           \
            const int row = g * 8 + lrow;                                      \
            GLDS16(kb0 + (size_t)(s0_ + row) * CC + swz, &Ks[bi_][g * 8][0]);  \
            GLDS16(vb0 + (size_t)row * TT + s0_ + swz, &Vs[bi_][g * 8][0]);    \
        }                                                                      \
    } while (0)

    STAGE_KV(0, 0);
    __syncthreads();  // compiler emits vmcnt(0) before the barrier -> buf0 ready

    for (int kt = 0; kt < nkt; ++kt) {
        const int cur = kt & 1;
        // prefetch next tile into the buffer everyone just finished reading
        if (kt + 1 < nkt) STAGE_KV(kt + 1, cur ^ 1);

        const int s0 = kt * 64;
        if (s0 <= qw0 + 31) {  // wave-uniform: any unmasked element?
            const unsigned short (*Kc)[64] = Ks[cur];
            const unsigned short (*Vc)[64] = Vs[cur];
            // S^T = K Q^T : A=K[m=key], B=Q^T[k=d][n=q]; D row=key, col=q
            f32x4 st[2][4];
#pragma unroll
            for (int nt = 0; nt < 4; ++nt) {
                const int key = nt * 16 + l16;
                const s16x8 kf0 = *(const s16x8*)&Kc[key][((0 + quad) ^ (l16 & 7)) * 8];
                const s16x8 kf1 = *(const s16x8*)&Kc[key][((4 + quad) ^ (l16 & 7)) * 8];
#pragma unroll
                for (int qs = 0; qs < 2; ++qs) {
                    f32x4 acc = (f32x4){0.f, 0.f, 0.f, 0.f};
                    acc = __builtin_amdgcn_mfma_f32_16x16x32_bf16(kf0, qf[qs][0], acc, 0, 0, 0);
                    acc = __builtin_amdgcn_mfma_f32_16x16x32_bf16(kf1, qf[qs][1], acc, 0, 0, 0);
                    st[qs][nt] = acc;
                }
            }

            const bool maskedTile = (s0 + 63 > qw0);  // wave-uniform
            s16x8 pf[2][2];
#pragma unroll
            for (int qs = 0; qs < 2; ++qs) {
                const int qidx = qw0 + qs * 16 + l16;
                unsigned pc[4][2];
                float tsum = 0.f;
#pragma unroll
                for (int nt = 0; nt < 4; ++nt) {
                    const int key0 = s0 + nt * 16 + quad * 4;
                    float p[4];
#pragma unroll
                    for (int r = 0; r < 4; ++r) {
                        float sv = st[qs][nt][r];
                        if (maskedTile && (key0 + r > qidx)) sv = -1e30f;
                        p[r] = fast_exp2(sv);
                    }
                    tsum += (p[0] + p[1]) + (p[2] + p[3]);  // tree, short dep chain
                    pc[nt][0] = pack_bf16_trunc(p[0], p[1]);
                    pc[nt][1] = pack_bf16_trunc(p[2], p[3]);
                }
                lsum[qs] += tsum;
                // in-register P redistribution: quads exchange via permlane swaps
#pragma unroll
                for (int kh = 0; kh < 2; ++kh) {
                    auto s0a = __builtin_amdgcn_permlane32_swap(
                        (int)pc[2 * kh + 0][0], (int)pc[2 * kh + 1][0], false, false);
                    auto w02 = __builtin_amdgcn_permlane16_swap(s0a[0], s0a[1], false, false);
                    auto s1a = __builtin_amdgcn_permlane32_swap(
                        (int)pc[2 * kh + 0][1], (int)pc[2 * kh + 1][1], false, false);
                    auto w13 = __builtin_amdgcn_permlane16_swap(s1a[0], s1a[1], false, false);
                    union { unsigned u[4]; s16x8 v; } fu;
                    fu.u[0] = (unsigned)w02[0];  // keys +0,+1
                    fu.u[1] = (unsigned)w13[0];  // keys +2,+3
                    fu.u[2] = (unsigned)w02[1];  // keys +4,+5
                    fu.u[3] = (unsigned)w13[1];  // keys +6,+7
                    pf[qs][kh] = fu.v;
                }
            }

            // PV: A=P[m=q][k=key] in registers; B=V[k=key][n=dv] from Vs rows
#pragma unroll
            for (int nt = 0; nt < 4; ++nt) {
                const int dv = nt * 16 + l16;
                const s16x8 vf0 = *(const s16x8*)&Vc[dv][((0 + quad) ^ (l16 & 7)) * 8];
                const s16x8 vf1 = *(const s16x8*)&Vc[dv][((4 + quad) ^ (l16 & 7)) * 8];
#pragma unroll
                for (int qs = 0; qs < 2; ++qs) {
                    o[qs][nt] = __builtin_amdgcn_mfma_f32_16x16x32_bf16(pf[qs][0], vf0,
                                                                        o[qs][nt], 0, 0, 0);
                    o[qs][nt] = __builtin_amdgcn_mfma_f32_16x16x32_bf16(pf[qs][1], vf1,
                                                                        o[qs][nt], 0, 0, 0);
                }
            }
        }
        // single barrier per tile: all waves done reading buf[cur] AND
        // (via the implicit vmcnt(0) drain) tile kt+1 fully landed in buf[cur^1]
        __syncthreads();
    }

    // final l reduction: quads hold partial sums for query qs*16+l16
    float lfull[2];
#pragma unroll
    for (int qs = 0; qs < 2; ++qs) {
        float s = lsum[qs];
        s += __shfl_xor(s, 16);
        s += __shfl_xor(s, 32);
        lfull[qs] = s;
    }

    // store: o element = (query qs*16+quad*4+r, dv nt*16+l16)
#pragma unroll
    for (int qs = 0; qs < 2; ++qs) {
#pragma unroll
        for (int r = 0; r < 4; ++r) {
            const float inv = 1.f / __shfl(lfull[qs], quad * 4 + r);
            unsigned short* yb = y + ((size_t)b * TT + qw0 + qs * 16 + quad * 4 + r) * CC +
                                 h * DD + l16;
#pragma unroll
            for (int nt = 0; nt < 4; ++nt)
                yb[nt * 16] = f2bf(o[qs][nt][r] * inv);
        }
    }
}

extern "C" void kernel_launch(void* const* d_in, const int* in_sizes, int n_in,
                              void* d_out, int out_size, void* d_ws, size_t ws_size,
                              hipStream_t stream) {
    const float* x   = (const float*)d_in[0];
    const float* Wq  = (const float*)d_in[1];
    const float* Wkv = (const float*)d_in[2];
    const float* Wk  = (const float*)d_in[3];
    const float* Wv  = (const float*)d_in[4];
    const float* Wo  = (const float*)d_in[5];
    float* out = (float*)d_out;

    const int M = BB * TT;  // 8192
    unsigned short* p = (unsigned short*)d_ws;
    unsigned short* xb    = p; p += (size_t)M * CC;     // bf16 x
    unsigned short* qlatb = p; p += (size_t)M * QLD;    // fused q | latent
    unsigned short* kb    = p; p += (size_t)M * CC;
    unsigned short* vtb   = p; p += (size_t)M * CC;
    unsigned short* yb    = p; p += (size_t)M * CC;
    unsigned short* W1t   = p; p += (size_t)QLD * CC;   // [Wq^T ; Wkv^T]  [1280][1024]
    unsigned short* W2t   = p; p += (size_t)(2 * CC) * LL;  // [Wk^T ; Wv^T] [2048][256]
    unsigned short* Wot   = p; p += (size_t)CC * CC;

    const float qscale = 0.125f * 1.44269504f;  // 1/sqrt(64) * log2(e), folded into Wq

    fused_cvt<<<8896, 256, 0, stream>>>(x, xb, Wq, Wkv, Wk, Wv, Wo,
                                        W1t, W2t, Wot, qscale);
    // fused q|latent projection: [M,1280] = x @ [Wq | Wkv]
    bgemm<1><<<dim3(QLD / 128, M / 128), 256, 0, stream>>>(
        xb, W1t, qlatb, nullptr, M, QLD, CC, CC, QLD);
    // fused k|v up-projection (K=256, whole-K staged): k -> kb, v -> vtb (transposed)
    bgemm_k256<<<dim3(2 * CC / 128, M / 128), 256, 0, stream>>>(
        qlatb + CC, W2t, kb, vtb);
    mla_attn2<<<dim3(BB * HH, TT / 128), 256, 0, stream>>>(qlatb, kb, vtb, yb);
    bgemm<0><<<dim3(CC / 128, M / 128), 256, 0, stream>>>(
        yb, Wot, out, nullptr, M, CC, CC, CC, CC);
}